// Round 7
// baseline (112.743 us; speedup 1.0000x reference)
//
#include <hip/hip_runtime.h>
#include <hip/hip_bf16.h>

typedef __attribute__((ext_vector_type(8))) short bf16x8;
typedef __attribute__((ext_vector_type(8))) short s16x8;
typedef __attribute__((ext_vector_type(4))) float f32x4;
typedef __attribute__((ext_vector_type(16))) float f32x16;

static __device__ inline unsigned short f2bf(float f) {
    unsigned int u = __float_as_uint(f);
    unsigned int r = (u + 0x7fff + ((u >> 16) & 1)) >> 16;
    return (unsigned short)r;
}

// ---------------- prep 1: u + Etab + invZ (summed-area table, wave scans) ----------------
__global__ void k_etabz(const float* __restrict__ centers, const float* __restrict__ spreads,
                        float* __restrict__ Etab, float* __restrict__ invZ) {
    int h = blockIdx.x;
    __shared__ float E[63][64];
    __shared__ float S[64][65];

    float s00 = spreads[h*4+0], s01 = spreads[h*4+1];
    float s10 = spreads[h*4+2], s11 = spreads[h*4+3];
    float a  = s00*s00 + s01*s01;
    float bb = s00*s10 + s01*s11;
    float c  = s10*s10 + s11*s11;
    float m1 = centers[h*2+0], m2 = centers[h*2+1];
    float u0 = a*m1 + bb*m2, u1 = c*m2 + bb*m1;
    float u2 = -0.5f*a, u3 = -0.5f*c, u4 = -bb;

    int tid = threadIdx.x, lane = tid & 63, w = tid >> 6;
    for (int idx = tid; idx < 4032; idx += 256) {       // 63 rows x 64 (pad col)
        int dk = idx >> 6, dl = idx & 63;
        if (dl < 63) {
            float d1 = (float)(dk - 31), d2 = (float)(dl - 31);
            float g = d1*u0 + d2*u1 + d1*d1*u2 + d2*d2*u3 + d1*d2*u4;
            float e = expf(g);
            E[dk][dl] = e;
            Etab[h*3969 + dk*63 + dl] = e;
        }
    }
    if (tid < 65) S[0][tid] = 0.f;
    if (tid < 64) S[tid][0] = 0.f;
    __syncthreads();
    for (int r = w; r < 63; r += 4) {                    // row inclusive scans
        float x = (lane < 63) ? E[r][lane] : 0.f;
        #pragma unroll
        for (int off = 1; off < 64; off <<= 1) {
            float nbr = __shfl_up(x, off);
            if (lane >= off) x += nbr;
        }
        if (lane < 63) S[r+1][lane+1] = x;
    }
    __syncthreads();
    for (int cc = 1 + w; cc < 64; cc += 4) {             // column inclusive scans
        float x = (lane < 63) ? S[lane+1][cc] : 0.f;
        #pragma unroll
        for (int off = 1; off < 64; off <<= 1) {
            float nbr = __shfl_up(x, off);
            if (lane >= off) x += nbr;
        }
        if (lane < 63) S[lane+1][cc] = x;
    }
    __syncthreads();
    for (int ij = tid; ij < 1024; ij += 256) {
        int i = ij >> 5, j = ij & 31;
        float Z = S[63-i][63-j] - S[31-i][63-j] - S[63-i][31-j] + S[31-i][31-j];
        invZ[ij*8 + h] = 1.0f / Z;
    }
}

// ---------------- prep 2: X transpose->bf16 | fc_w->bf16 | windowed P2 (table) ----------------
// P2[r][dk'*32+l] = bf16(Etab[h][k-i+31][l-j+31] * invZ[r]), k = klo(i)+dk',
// klo = clamp(i-6, 0, 20), window width 12 (K=384). Dropped |dk|>=6 weights <= e^-12.5/Z.
__global__ void k_prep(const float* __restrict__ X, const float* __restrict__ fc_w,
                       const float* __restrict__ Etab, const float* __restrict__ invZ,
                       unsigned short* __restrict__ X2, unsigned short* __restrict__ fcwb,
                       unsigned short* __restrict__ P2) {
    int bx = blockIdx.x, tid = threadIdx.x;
    if (bx < 512) {
        __shared__ float t[64][65];
        int b = bx >> 4, kl0 = (bx & 15) * 64;
        const float4* Xb4 = (const float4*)(X + (size_t)b * 65536 + (size_t)kl0 * 64);
        #pragma unroll
        for (int it = 0; it < 4; ++it) {
            int f4 = it*256 + tid;            // [0,1024): 64 kl x 16 float4
            int kl = f4 >> 4, e0 = (f4 & 15) << 2;
            float4 v = Xb4[f4];
            t[e0][kl] = v.x; t[e0+1][kl] = v.y; t[e0+2][kl] = v.z; t[e0+3][kl] = v.w;
        }
        __syncthreads();
        #pragma unroll
        for (int it = 0; it < 2; ++it) {
            int c = it*256 + tid;             // [0,512): 64 e x 8 chunks
            int e = c >> 3, c0 = (c & 7) << 3;
            s16x8 o;
            #pragma unroll
            for (int q = 0; q < 8; ++q) o[q] = (short)f2bf(t[e][c0 + q]);
            *(s16x8*)(X2 + ((size_t)(b*64 + e) << 10) + kl0 + c0) = o;
        }
    } else if (bx < 544) {
        int idx = (bx - 512)*1024 + tid*4;
        float4 v = *(const float4*)(fc_w + idx);
        ushort4 o;
        o.x = f2bf(v.x); o.y = f2bf(v.y); o.z = f2bf(v.z); o.w = f2bf(v.w);
        *(ushort4*)(fcwb + idx) = o;
    } else {
        int tt = (bx - 544)*256 + tid;        // [0, 393216): 8192 rows x 48 chunks
        int r = tt / 48, g = tt - r*48;
        int c0 = g * 8;                        // col in [0,384)
        int dkp = c0 >> 5, l0 = c0 & 31;
        int ij = r >> 3, h = r & 7;
        int i = ij >> 5, j = ij & 31;
        int klo = i - 6; klo = klo < 0 ? 0 : (klo > 20 ? 20 : klo);
        int k = klo + dkp;
        const float* Ep = Etab + h*3969 + (k - i + 31)*63 + (l0 - j + 31);
        float z = invZ[r];
        s16x8 o;
        #pragma unroll
        for (int q = 0; q < 8; ++q) o[q] = (short)f2bf(Ep[q]*z);
        *(s16x8*)(P2 + (size_t)r * 384 + c0) = o;
    }
}

// ---------------- main GEMM: tile 256(M) x 128(N), BK=32, K=384, 8 waves ----------------
// wave tile 64x64 (4Mx2N waves), mfma_f32_32x32x16_bf16. 3-buffer LDS (72KB) + epilogue
// union -> 2 blocks/CU. Counted vmcnt(3), 2-tiles-ahead, one fenced barrier per K-tile
// (proven invariant: buffers {read t%3, landing (t+1)%3, issuing (t+2)%3} distinct).
__global__ __launch_bounds__(512, 4) void k_gemm(const unsigned short* __restrict__ P2,
                                                 const unsigned short* __restrict__ X2,
                                                 const unsigned short* __restrict__ fcwb,
                                                 const float* __restrict__ fc_b,
                                                 float* __restrict__ out) {
    union Sh {
        struct { short A[3][256*32]; short B[3][128*32]; } s;  // 72 KiB
        short AHe[64*520];                                      // 66,560 B
    };
    __shared__ Sh sh;

    int tid = threadIdx.x;
    int lane = tid & 63, wid = tid >> 6;
    int ar = lane & 31, kg = lane >> 5;
    int i_g = blockIdx.x;                      // M block: rows r = i_g*256 + (j*8+h)
    int n0 = blockIdx.y * 128;
    int klo = i_g - 6; klo = klo < 0 ? 0 : (klo > 20 ? 20 : klo);
    int wr = wid >> 1, wc = wid & 1;           // wave tile: rows [wr*64,+64), cols [wc*64,+64)

    // staging: LDS dest linear; global source XOR-pre-swizzled (cs = c ^ ((row>>1)&3))
    const unsigned short* gA[2];
    const unsigned short* gB;
    int aoff[2], boffv;
    #pragma unroll
    for (int it = 0; it < 2; ++it) {
        int chunk = it*512 + tid;              // A: 1024 chunks (256 rows x 4)
        int r = chunk >> 2, c = chunk & 3;
        int cs = c ^ ((r >> 1) & 3);
        gA[it] = P2 + (size_t)(i_g*256 + r) * 384 + (cs << 3);
        aoff[it] = chunk * 8;
    }
    {
        int r = tid >> 2, c = tid & 3;         // B: 512 chunks (128 rows x 4)
        int cs = c ^ ((r >> 1) & 3);
        gB = X2 + ((size_t)(n0 + r) << 10) + (klo << 5) + (cs << 3);
        boffv = tid * 8;
    }

#define STAGE(nb, tt) do { \
    _Pragma("unroll") \
    for (int it = 0; it < 2; ++it) \
        __builtin_amdgcn_global_load_lds( \
            (const __attribute__((address_space(1))) void*)(gA[it] + (tt)*32), \
            (__attribute__((address_space(3))) void*)(&sh.s.A[nb][aoff[it]]), 16, 0, 0); \
    __builtin_amdgcn_global_load_lds( \
        (const __attribute__((address_space(1))) void*)(gB + (tt)*32), \
        (__attribute__((address_space(3))) void*)(&sh.s.B[nb][boffv]), 16, 0, 0); \
} while (0)

    f32x16 acc00 = {}, acc01 = {}, acc10 = {}, acc11 = {};

    // prologue: 2-deep prefetch; vmcnt(3) = tile0's 3 loads done, tile1's 3 in flight
    STAGE(0, 0);
    STAGE(1, 1);
    asm volatile("s_waitcnt vmcnt(3)" ::: "memory");
    __builtin_amdgcn_s_barrier();
    __builtin_amdgcn_sched_barrier(0);

    int cb = 0, nb = 2;
    #pragma unroll 1
    for (int t = 0; t < 12; ++t) {
        if (t < 10) STAGE(nb, t + 2);          // issue-early; lands during this tile's MFMAs
        const short* Ab = &sh.s.A[cb][0];
        const short* Bb = &sh.s.B[cb][0];
        #pragma unroll
        for (int kk = 0; kk < 2; ++kk) {
            int c = kk*2 + kg;
            int rowA0 = wr*64 + ar,      rowA1 = wr*64 + 32 + ar;
            int colB0 = wc*64 + ar,      colB1 = wc*64 + 32 + ar;
            bf16x8 a0 = *(const bf16x8*)&Ab[rowA0*32 + (c ^ ((rowA0 >> 1) & 3))*8];
            bf16x8 a1 = *(const bf16x8*)&Ab[rowA1*32 + (c ^ ((rowA1 >> 1) & 3))*8];
            bf16x8 b0 = *(const bf16x8*)&Bb[colB0*32 + (c ^ ((colB0 >> 1) & 3))*8];
            bf16x8 b1 = *(const bf16x8*)&Bb[colB1*32 + (c ^ ((colB1 >> 1) & 3))*8];
            __builtin_amdgcn_s_setprio(1);
            acc00 = __builtin_amdgcn_mfma_f32_32x32x16_bf16(a0, b0, acc00, 0, 0, 0);
            acc01 = __builtin_amdgcn_mfma_f32_32x32x16_bf16(a0, b1, acc01, 0, 0, 0);
            acc10 = __builtin_amdgcn_mfma_f32_32x32x16_bf16(a1, b0, acc10, 0, 0, 0);
            acc11 = __builtin_amdgcn_mfma_f32_32x32x16_bf16(a1, b1, acc11, 0, 0, 0);
            __builtin_amdgcn_s_setprio(0);
        }
        // steady state: tile t+1's 3 loads must be done; tile t+2's 3 stay in flight
        if (t < 10) asm volatile("s_waitcnt vmcnt(3)" ::: "memory");
        else        asm volatile("s_waitcnt vmcnt(0)" ::: "memory");
        __builtin_amdgcn_s_barrier();
        __builtin_amdgcn_sched_barrier(0);
        cb = (cb == 2) ? 0 : cb + 1;
        nb = (nb == 2) ? 0 : nb + 1;
    }
#undef STAGE

    __syncthreads();   // before LDS reuse

    // scatter acc -> AHe[(b_lo*32+j)_local][e*8+h]; 32x32 C-layout:
    // col = lane&31, row = (reg&3) + 8*(reg>>2) + 4*(lane>>5)
    #pragma unroll
    for (int mt = 0; mt < 2; ++mt) {
        #pragma unroll
        for (int nt = 0; nt < 2; ++nt) {
            const f32x16* A = (mt == 0) ? (nt == 0 ? &acc00 : &acc01)
                                        : (nt == 0 ? &acc10 : &acc11);
            int colC = wc*64 + nt*32 + ar;
            int eL = colC & 63;
            #pragma unroll
            for (int rg = 0; rg < 4; ++rg) {
                int rbase = wr*64 + mt*32 + 8*rg + 4*kg;
                int jj = rbase >> 3, hh0 = rbase & 7;
                ushort4 pk;
                pk.x = f2bf((*A)[rg*4+0]); pk.y = f2bf((*A)[rg*4+1]);
                pk.z = f2bf((*A)[rg*4+2]); pk.w = f2bf((*A)[rg*4+3]);
                *(ushort4*)&sh.AHe[(wc*32 + jj)*520 + eL*8 + hh0] = pk;
            }
        }
    }
    __syncthreads();

    // mini-GEMM (16x16x32): out2[r2][e'] = sum_f AHe[r2][f]*fcwb[e'][f]; M=64,N=64,K=512
    int lr16 = lane & 15, lk16 = lane >> 4;
    int fm = wid >> 1, fn = wid & 1;
    f32x4 facc0 = {}, facc1 = {};
    #pragma unroll
    for (int ks = 0; ks < 16; ++ks) {
        int koff = ks*32 + lk16*8;
        bf16x8 a  = *(const bf16x8*)&sh.AHe[(fm*16 + lr16)*520 + koff];
        bf16x8 b0 = *(const bf16x8*)&fcwb[(size_t)(fn*32 + lr16)*512 + koff];
        bf16x8 b1 = *(const bf16x8*)&fcwb[(size_t)(fn*32 + 16 + lr16)*512 + koff];
        facc0 = __builtin_amdgcn_mfma_f32_16x16x32_bf16(a, b0, facc0, 0, 0, 0);
        facc1 = __builtin_amdgcn_mfma_f32_16x16x32_bf16(a, b1, facc1, 0, 0, 0);
    }

    int b0g = blockIdx.y * 2;
    #pragma unroll
    for (int an = 0; an < 2; ++an) {
        int ecol = fn*32 + an*16 + lr16;
        float bias = fc_b[ecol];
        const f32x4* F = an ? &facc1 : &facc0;
        #pragma unroll
        for (int reg = 0; reg < 4; ++reg) {
            int r2 = fm*16 + lk16*4 + reg;         // [0,64)
            int b = b0g + (r2 >> 5), jj = r2 & 31;
            size_t o = (((size_t)(b*32 + i_g))*32 + jj)*64 + ecol;
            out[o] = (*F)[reg] + bias;
        }
    }
}

extern "C" void kernel_launch(void* const* d_in, const int* in_sizes, int n_in,
                              void* d_out, int out_size, void* d_ws, size_t ws_size,
                              hipStream_t stream) {
    const float* X       = (const float*)d_in[0];
    const float* centers = (const float*)d_in[2];
    const float* spreads = (const float*)d_in[3];
    const float* fc_w    = (const float*)d_in[4];
    const float* fc_b    = (const float*)d_in[5];
    float* out = (float*)d_out;

    char* ws = (char*)d_ws;
    float* Etab          = (float*)(ws + 4096);                // 127 KB
    float* invZ          = (float*)(ws + (144 << 10));         // 32 KB
    unsigned short* fcwb = (unsigned short*)(ws + (256 << 10));// 64 KB
    unsigned short* X2   = (unsigned short*)(ws + (512 << 10));// 4 MB
    unsigned short* P2   = (unsigned short*)(ws + (5 << 20));  // 6 MB (8192 x 384)

    k_etabz <<<8, 256, 0, stream>>>(centers, spreads, Etab, invZ);
    k_prep  <<<2080, 256, 0, stream>>>(X, fc_w, Etab, invZ, X2, fcwb, P2);
    k_gemm  <<<dim3(32, 16), 512, 0, stream>>>(P2, X2, fcwb, fc_b, out);
}

// Round 8
// 98.249 us; speedup vs baseline: 1.1475x; 1.1475x over previous
//
#include <hip/hip_runtime.h>
#include <hip/hip_bf16.h>

typedef __attribute__((ext_vector_type(8))) short bf16x8;
typedef __attribute__((ext_vector_type(8))) short s16x8;
typedef __attribute__((ext_vector_type(4))) float f32x4;

static __device__ inline unsigned short f2bf(float f) {
    unsigned int u = __float_as_uint(f);
    unsigned int r = (u + 0x7fff + ((u >> 16) & 1)) >> 16;
    return (unsigned short)r;
}

// ---------------- unified prep: X transpose->bf16 | fc_w->bf16 | windowed P2, inline Z ----
// P2[r][dk'*32+l] = bf16(exp(g_h(k-i,l-j)) / Z(ij,h)), k = klo(i)+dk', klo = clamp(i-6,0,20),
// window 12 (K=384). Z = full 1024-term softmax denom, computed per block (R6-validated).
__global__ void k_prep(const float* __restrict__ X, const float* __restrict__ fc_w,
                       const float* __restrict__ centers, const float* __restrict__ spreads,
                       unsigned short* __restrict__ X2, unsigned short* __restrict__ fcwb,
                       unsigned short* __restrict__ P2) {
    int bx = blockIdx.x, tid = threadIdx.x;
    if (bx < 512) {
        __shared__ float t[64][65];
        int b = bx >> 4, kl0 = (bx & 15) * 64;
        const float4* Xb4 = (const float4*)(X + (size_t)b * 65536 + (size_t)kl0 * 64);
        #pragma unroll
        for (int it = 0; it < 4; ++it) {
            int f4 = it*256 + tid;            // [0,1024): 64 kl x 16 float4
            int kl = f4 >> 4, e0 = (f4 & 15) << 2;
            float4 v = Xb4[f4];
            t[e0][kl] = v.x; t[e0+1][kl] = v.y; t[e0+2][kl] = v.z; t[e0+3][kl] = v.w;
        }
        __syncthreads();
        #pragma unroll
        for (int it = 0; it < 2; ++it) {
            int c = it*256 + tid;             // [0,512): 64 e x 8 chunks
            int e = c >> 3, c0 = (c & 7) << 3;
            s16x8 o;
            #pragma unroll
            for (int q = 0; q < 8; ++q) o[q] = (short)f2bf(t[e][c0 + q]);
            *(s16x8*)(X2 + ((size_t)(b*64 + e) << 10) + kl0 + c0) = o;
        }
    } else if (bx < 544) {
        int idx = (bx - 512)*1024 + tid*4;
        float4 v = *(const float4*)(fc_w + idx);
        ushort4 o;
        o.x = f2bf(v.x); o.y = f2bf(v.y); o.z = f2bf(v.z); o.w = f2bf(v.w);
        *(ushort4*)(fcwb + idx) = o;
    } else {
        int pix = bx - 544;                   // [0,2048): one (i,j), 4 heads
        int ij = pix >> 1, h0 = (pix & 1) * 4;
        int i = ij >> 5, j = ij & 31;
        int lane = tid & 63, w = tid >> 6;
        int hq = h0 + w;
        float s00 = spreads[hq*4+0], s01 = spreads[hq*4+1];
        float s10 = spreads[hq*4+2], s11 = spreads[hq*4+3];
        float a  = s00*s00 + s01*s01;
        float bb = s00*s10 + s01*s11;
        float cc = s10*s10 + s11*s11;
        float m1 = centers[hq*2+0], m2 = centers[hq*2+1];
        float u0 = a*m1 + bb*m2, u1 = cc*m2 + bb*m1;
        float u2 = -0.5f*a, u3 = -0.5f*cc, u4 = -bb;
        // Z = softmax denominator over the full 32x32 grid
        float zs = 0.f;
        #pragma unroll
        for (int e = 0; e < 16; ++e) {
            int kl = e*64 + lane;
            float d1 = (float)((kl >> 5) - i), d2 = (float)((kl & 31) - j);
            zs += expf(d1*u0 + d2*u1 + d1*d1*u2 + d2*d2*u3 + d1*d2*u4);
        }
        #pragma unroll
        for (int m = 32; m >= 1; m >>= 1) zs += __shfl_xor(zs, m);
        __shared__ float Zs[4];
        if (lane == 0) Zs[w] = 1.0f / zs;
        __syncthreads();
        float invz = Zs[w];
        if (lane < 48) {                       // 48 chunks x 8 = 384 cols
            int col0 = lane * 8;
            int klo = i - 6; klo = klo < 0 ? 0 : (klo > 20 ? 20 : klo);
            float d1 = (float)(klo + (col0 >> 5) - i);
            int l0 = col0 & 31;
            float base1 = d1*u0 + d1*d1*u2;
            s16x8 o;
            #pragma unroll
            for (int q = 0; q < 8; ++q) {
                float d2 = (float)(l0 + q - j);
                o[q] = (short)f2bf(expf(base1 + d2*u1 + d2*d2*u3 + d1*d2*u4) * invz);
            }
            *(s16x8*)(P2 + (size_t)(ij*8 + hq) * 384 + col0) = o;
        }
    }
}

// ---------------- main GEMM: R5's proven structure, K=384 ----------------
// tile 256x256, BK=32, 12 K-tiles, 8 waves (wave tile 128x64), 16x16x32 MFMA.
// 3-buffer LDS, 2-tiles-ahead staging, counted vmcnt(4) (never 0 in steady state),
// one barrier per K-tile, memory-clobbered waitcnt before + sched_barrier(0) after.
__global__ __launch_bounds__(512) void k_gemm(const unsigned short* __restrict__ P2,
                                              const unsigned short* __restrict__ X2,
                                              const unsigned short* __restrict__ fcwb,
                                              const float* __restrict__ fc_b,
                                              float* __restrict__ out) {
    union Sh {
        struct { short A[3][256*32]; short B[3][256*32]; } s;  // 96 KiB
        short AHe[128*520];                                     // 130 KiB (epilogue)
    };
    __shared__ Sh sh;

    int tid = threadIdx.x;
    int lane = tid & 63, wid = tid >> 6;
    int lr = lane & 15, lk = lane >> 4;
    int i_g = blockIdx.x;                  // fixed i; rows r = i_g*256 + (j*8+h)
    int m0 = i_g * 256, n0 = blockIdx.y * 256;
    int klo = i_g - 6; klo = klo < 0 ? 0 : (klo > 20 ? 20 : klo);
    int wr = wid >> 2, wc = wid & 3;       // wave tile: rows [wr*128,+128), cols [wc*64,+64)

    // staging: LDS dest linear per-wave; global source XOR-pre-swizzled
    // (4 x 16B chunks per 64B LDS row; cs = c ^ ((row>>1)&3))
    const unsigned short* gA[2]; int aoff[2];
    const unsigned short* gB[2]; int boff[2];
    #pragma unroll
    for (int it = 0; it < 2; ++it) {
        int chunk = it*512 + tid;          // [0,1024)
        int r = chunk >> 2, c = chunk & 3;
        int cs = c ^ ((r >> 1) & 3);
        gA[it] = P2 + (size_t)(m0 + r) * 384 + (cs << 3);
        gB[it] = X2 + ((size_t)(n0 + r) << 10) + (klo << 5) + (cs << 3);
        aoff[it] = (it*512 + wid*64) * 8;
        boff[it] = (it*512 + wid*64) * 8;
    }

#define STAGE(nb, tt) do { \
    _Pragma("unroll") \
    for (int it = 0; it < 2; ++it) \
        __builtin_amdgcn_global_load_lds( \
            (const __attribute__((address_space(1))) void*)(gA[it] + (tt)*32), \
            (__attribute__((address_space(3))) void*)(&sh.s.A[nb][aoff[it]]), 16, 0, 0); \
    _Pragma("unroll") \
    for (int it = 0; it < 2; ++it) \
        __builtin_amdgcn_global_load_lds( \
            (const __attribute__((address_space(1))) void*)(gB[it] + (tt)*32), \
            (__attribute__((address_space(3))) void*)(&sh.s.B[nb][boff[it]]), 16, 0, 0); \
} while (0)

    f32x4 acc[8][4] = {};

    // prologue: 2-deep prefetch; vmcnt(4) = tile0's 4 loads done, tile1's in flight
    STAGE(0, 0);
    STAGE(1, 1);
    asm volatile("s_waitcnt vmcnt(4)" ::: "memory");
    __builtin_amdgcn_s_barrier();
    __builtin_amdgcn_sched_barrier(0);

    int cb = 0, nb = 2;
    #pragma unroll 1
    for (int t = 0; t < 12; ++t) {
        const short* Ab = &sh.s.A[cb][0];
        const short* Bb = &sh.s.B[cb][0];
        bf16x8 av[4], bv[4];
        #pragma unroll
        for (int n = 0; n < 4; ++n) {
            int col = wc*64 + n*16 + lr;
            int cs = lk ^ ((col >> 1) & 3);
            bv[n] = *(const bf16x8*)&Bb[col*32 + cs*8];
        }
        #pragma unroll
        for (int m = 0; m < 4; ++m) {
            int row = wr*128 + m*16 + lr;
            int cs = lk ^ ((row >> 1) & 3);
            av[m] = *(const bf16x8*)&Ab[row*32 + cs*8];
        }
        if (t < 10) STAGE(nb, t + 2);      // issue-early: latency hides under MFMAs
        __builtin_amdgcn_s_setprio(1);
        #pragma unroll
        for (int m = 0; m < 4; ++m)
            #pragma unroll
            for (int n = 0; n < 4; ++n)
                acc[m][n] = __builtin_amdgcn_mfma_f32_16x16x32_bf16(av[m], bv[n], acc[m][n], 0, 0, 0);
        __builtin_amdgcn_s_setprio(0);
        #pragma unroll
        for (int m = 0; m < 4; ++m) {
            int row = wr*128 + 64 + m*16 + lr;
            int cs = lk ^ ((row >> 1) & 3);
            av[m] = *(const bf16x8*)&Ab[row*32 + cs*8];
        }
        __builtin_amdgcn_s_setprio(1);
        #pragma unroll
        for (int m = 0; m < 4; ++m)
            #pragma unroll
            for (int n = 0; n < 4; ++n)
                acc[4 + m][n] = __builtin_amdgcn_mfma_f32_16x16x32_bf16(av[m], bv[n], acc[4 + m][n], 0, 0, 0);
        __builtin_amdgcn_s_setprio(0);
        // steady state: tile t+1's 4 loads must be done; tile t+2's 4 stay in flight
        if (t < 10) asm volatile("s_waitcnt vmcnt(4)" ::: "memory");
        else        asm volatile("s_waitcnt vmcnt(0)" ::: "memory");
        __builtin_amdgcn_s_barrier();
        __builtin_amdgcn_sched_barrier(0);
        cb = (cb == 2) ? 0 : cb + 1;
        nb = (nb == 2) ? 0 : nb + 1;
    }
#undef STAGE

    __syncthreads();   // full drain before LDS reuse

    // scatter acc -> AHe[(b,j)_local][e*8+h] as bf16 (packed 4-h ds_write_b64)
    #pragma unroll
    for (int m = 0; m < 8; ++m) {
        #pragma unroll
        for (int n = 0; n < 4; ++n) {
            int colC = wc*64 + n*16 + lr;        // (b,e) local
            int bb2 = colC >> 6, e = colC & 63;
            int rowC0 = wr*128 + m*16 + lk*4;    // (j,h) local, 4 consecutive h
            int jj = rowC0 >> 3, h0 = rowC0 & 7;
            ushort4 pk;
            pk.x = f2bf(acc[m][n][0]); pk.y = f2bf(acc[m][n][1]);
            pk.z = f2bf(acc[m][n][2]); pk.w = f2bf(acc[m][n][3]);
            *(ushort4*)&sh.AHe[(bb2*32 + jj)*520 + e*8 + h0] = pk;
        }
    }
    __syncthreads();

    // mini-GEMM: out2[r2][e'] = sum_f AHe[r2][f] * fcwb[e'][f]; M=128, N=64, K=512
    int fm = wid >> 1, fn = wid & 1;
    f32x4 facc[2][2] = {};
    #pragma unroll
    for (int ks = 0; ks < 16; ++ks) {
        int koff = ks*32 + lk*8;
        bf16x8 a0 = *(const bf16x8*)&sh.AHe[(fm*32 + lr)*520 + koff];
        bf16x8 a1 = *(const bf16x8*)&sh.AHe[(fm*32 + 16 + lr)*520 + koff];
        bf16x8 b0 = *(const bf16x8*)&fcwb[(size_t)(fn*32 + lr)*512 + koff];
        bf16x8 b1 = *(const bf16x8*)&fcwb[(size_t)(fn*32 + 16 + lr)*512 + koff];
        facc[0][0] = __builtin_amdgcn_mfma_f32_16x16x32_bf16(a0, b0, facc[0][0], 0, 0, 0);
        facc[0][1] = __builtin_amdgcn_mfma_f32_16x16x32_bf16(a0, b1, facc[0][1], 0, 0, 0);
        facc[1][0] = __builtin_amdgcn_mfma_f32_16x16x32_bf16(a1, b0, facc[1][0], 0, 0, 0);
        facc[1][1] = __builtin_amdgcn_mfma_f32_16x16x32_bf16(a1, b1, facc[1][1], 0, 0, 0);
    }

    int b0g = blockIdx.y * 4;
    float bias0 = fc_b[fn*32 + lr];
    float bias1 = fc_b[fn*32 + 16 + lr];
    #pragma unroll
    for (int am = 0; am < 2; ++am) {
        #pragma unroll
        for (int an = 0; an < 2; ++an) {
            int ecol = fn*32 + an*16 + lr;
            float bias = an ? bias1 : bias0;
            #pragma unroll
            for (int reg = 0; reg < 4; ++reg) {
                int r2 = fm*32 + am*16 + lk*4 + reg;
                int bb2 = r2 >> 5, jj = r2 & 31;
                size_t o = (((size_t)((b0g + bb2)*32 + i_g))*32 + jj)*64 + ecol;
                out[o] = facc[am][an][reg] + bias;
            }
        }
    }
}

extern "C" void kernel_launch(void* const* d_in, const int* in_sizes, int n_in,
                              void* d_out, int out_size, void* d_ws, size_t ws_size,
                              hipStream_t stream) {
    const float* X       = (const float*)d_in[0];
    const float* centers = (const float*)d_in[2];
    const float* spreads = (const float*)d_in[3];
    const float* fc_w    = (const float*)d_in[4];
    const float* fc_b    = (const float*)d_in[5];
    float* out = (float*)d_out;

    char* ws = (char*)d_ws;
    unsigned short* fcwb = (unsigned short*)ws;                 // 64 KB
    unsigned short* X2   = (unsigned short*)(ws + (1 << 20));   // 4 MB
    unsigned short* P2   = (unsigned short*)(ws + (6 << 20));   // 6.3 MB (8192 x 384)

    k_prep <<<2592, 256, 0, stream>>>(X, fc_w, centers, spreads, X2, fcwb, P2);
    k_gemm <<<dim3(32, 8), 512, 0, stream>>>(P2, X2, fcwb, fc_b, out);
}

// Round 9
// 97.507 us; speedup vs baseline: 1.1563x; 1.0076x over previous
//
#include <hip/hip_runtime.h>
#include <hip/hip_bf16.h>

typedef __attribute__((ext_vector_type(8))) short bf16x8;
typedef __attribute__((ext_vector_type(8))) short s16x8;
typedef __attribute__((ext_vector_type(4))) float f32x4;

static __device__ inline unsigned short f2bf(float f) {
    unsigned int u = __float_as_uint(f);
    unsigned int r = (u + 0x7fff + ((u >> 16) & 1)) >> 16;
    return (unsigned short)r;
}

// ---------------- unified prep: X transpose->bf16 | fc_w->bf16 | windowed P2, inline Z ----
// P2[r][dk'*32+l] = bf16(exp(g_h(k-i,l-j)) / Z(ij,h)), k = klo(i)+dk', klo = clamp(i-4,0,24),
// window 8 (K=256). Dropped |dk|>=4 terms have weight <= e^-8/Z (~5e-5 each, ~5e-4 total mass).
__global__ void k_prep(const float* __restrict__ X, const float* __restrict__ fc_w,
                       const float* __restrict__ centers, const float* __restrict__ spreads,
                       unsigned short* __restrict__ X2, unsigned short* __restrict__ fcwb,
                       unsigned short* __restrict__ P2) {
    int bx = blockIdx.x, tid = threadIdx.x;
    if (bx < 512) {
        __shared__ float t[64][65];
        int b = bx >> 4, kl0 = (bx & 15) * 64;
        const float4* Xb4 = (const float4*)(X + (size_t)b * 65536 + (size_t)kl0 * 64);
        #pragma unroll
        for (int it = 0; it < 4; ++it) {
            int f4 = it*256 + tid;            // [0,1024): 64 kl x 16 float4
            int kl = f4 >> 4, e0 = (f4 & 15) << 2;
            float4 v = Xb4[f4];
            t[e0][kl] = v.x; t[e0+1][kl] = v.y; t[e0+2][kl] = v.z; t[e0+3][kl] = v.w;
        }
        __syncthreads();
        #pragma unroll
        for (int it = 0; it < 2; ++it) {
            int c = it*256 + tid;             // [0,512): 64 e x 8 chunks
            int e = c >> 3, c0 = (c & 7) << 3;
            s16x8 o;
            #pragma unroll
            for (int q = 0; q < 8; ++q) o[q] = (short)f2bf(t[e][c0 + q]);
            *(s16x8*)(X2 + ((size_t)(b*64 + e) << 10) + kl0 + c0) = o;
        }
    } else if (bx < 544) {
        int idx = (bx - 512)*1024 + tid*4;
        float4 v = *(const float4*)(fc_w + idx);
        ushort4 o;
        o.x = f2bf(v.x); o.y = f2bf(v.y); o.z = f2bf(v.z); o.w = f2bf(v.w);
        *(ushort4*)(fcwb + idx) = o;
    } else {
        int pix = bx - 544;                   // [0,2048): one (i,j), 4 heads
        int ij = pix >> 1, h0 = (pix & 1) * 4;
        int i = ij >> 5, j = ij & 31;
        int lane = tid & 63, w = tid >> 6;
        int hq = h0 + w;
        float s00 = spreads[hq*4+0], s01 = spreads[hq*4+1];
        float s10 = spreads[hq*4+2], s11 = spreads[hq*4+3];
        float a  = s00*s00 + s01*s01;
        float bb = s00*s10 + s01*s11;
        float cc = s10*s10 + s11*s11;
        float m1 = centers[hq*2+0], m2 = centers[hq*2+1];
        float u0 = a*m1 + bb*m2, u1 = cc*m2 + bb*m1;
        float u2 = -0.5f*a, u3 = -0.5f*cc, u4 = -bb;
        // Z = softmax denominator over the full 32x32 grid
        float zs = 0.f;
        #pragma unroll
        for (int e = 0; e < 16; ++e) {
            int kl = e*64 + lane;
            float d1 = (float)((kl >> 5) - i), d2 = (float)((kl & 31) - j);
            zs += expf(d1*u0 + d2*u1 + d1*d1*u2 + d2*d2*u3 + d1*d2*u4);
        }
        #pragma unroll
        for (int m = 32; m >= 1; m >>= 1) zs += __shfl_xor(zs, m);
        __shared__ float Zs[4];
        if (lane == 0) Zs[w] = 1.0f / zs;
        __syncthreads();
        float invz = Zs[w];
        if (lane < 32) {                       // 32 chunks x 8 = 256 cols
            int col0 = lane * 8;
            int klo = i - 4; klo = klo < 0 ? 0 : (klo > 24 ? 24 : klo);
            float d1 = (float)(klo + (col0 >> 5) - i);
            int l0 = col0 & 31;
            float base1 = d1*u0 + d1*d1*u2;
            s16x8 o;
            #pragma unroll
            for (int q = 0; q < 8; ++q) {
                float d2 = (float)(l0 + q - j);
                o[q] = (short)f2bf(expf(base1 + d2*u1 + d2*d2*u3 + d1*d2*u4) * invz);
            }
            *(s16x8*)(P2 + ((size_t)(ij*8 + hq) << 8) + col0) = o;
        }
    }
}

// ---------------- main GEMM: R5/R8's proven structure, K=256 ----------------
// tile 256x256, BK=32, 8 K-tiles, 8 waves (wave tile 128x64), 16x16x32 MFMA.
// 3-buffer LDS, 2-tiles-ahead staging, counted vmcnt(4) (never 0 in steady state),
// one barrier per K-tile, memory-clobbered waitcnt before + sched_barrier(0) after.
__global__ __launch_bounds__(512) void k_gemm(const unsigned short* __restrict__ P2,
                                              const unsigned short* __restrict__ X2,
                                              const unsigned short* __restrict__ fcwb,
                                              const float* __restrict__ fc_b,
                                              float* __restrict__ out) {
    union Sh {
        struct { short A[3][256*32]; short B[3][256*32]; } s;  // 96 KiB
        short AHe[128*520];                                     // 130 KiB (epilogue)
    };
    __shared__ Sh sh;

    int tid = threadIdx.x;
    int lane = tid & 63, wid = tid >> 6;
    int lr = lane & 15, lk = lane >> 4;
    int i_g = blockIdx.x;                  // fixed i; rows r = i_g*256 + (j*8+h)
    int m0 = i_g * 256, n0 = blockIdx.y * 256;
    int klo = i_g - 4; klo = klo < 0 ? 0 : (klo > 24 ? 24 : klo);
    int wr = wid >> 2, wc = wid & 3;       // wave tile: rows [wr*128,+128), cols [wc*64,+64)

    // staging: LDS dest linear per-wave; global source XOR-pre-swizzled
    // (4 x 16B chunks per 64B LDS row; cs = c ^ ((row>>1)&3))
    const unsigned short* gA[2]; int aoff[2];
    const unsigned short* gB[2]; int boff[2];
    #pragma unroll
    for (int it = 0; it < 2; ++it) {
        int chunk = it*512 + tid;          // [0,1024)
        int r = chunk >> 2, c = chunk & 3;
        int cs = c ^ ((r >> 1) & 3);
        gA[it] = P2 + ((size_t)(m0 + r) << 8) + (cs << 3);
        gB[it] = X2 + ((size_t)(n0 + r) << 10) + (klo << 5) + (cs << 3);
        aoff[it] = (it*512 + wid*64) * 8;
        boff[it] = (it*512 + wid*64) * 8;
    }

#define STAGE(nb, tt) do { \
    _Pragma("unroll") \
    for (int it = 0; it < 2; ++it) \
        __builtin_amdgcn_global_load_lds( \
            (const __attribute__((address_space(1))) void*)(gA[it] + (tt)*32), \
            (__attribute__((address_space(3))) void*)(&sh.s.A[nb][aoff[it]]), 16, 0, 0); \
    _Pragma("unroll") \
    for (int it = 0; it < 2; ++it) \
        __builtin_amdgcn_global_load_lds( \
            (const __attribute__((address_space(1))) void*)(gB[it] + (tt)*32), \
            (__attribute__((address_space(3))) void*)(&sh.s.B[nb][boff[it]]), 16, 0, 0); \
} while (0)

    f32x4 acc[8][4] = {};

    // prologue: 2-deep prefetch; vmcnt(4) = tile0's 4 loads done, tile1's in flight
    STAGE(0, 0);
    STAGE(1, 1);
    asm volatile("s_waitcnt vmcnt(4)" ::: "memory");
    __builtin_amdgcn_s_barrier();
    __builtin_amdgcn_sched_barrier(0);

    int cb = 0, nb = 2;
    #pragma unroll 1
    for (int t = 0; t < 8; ++t) {
        const short* Ab = &sh.s.A[cb][0];
        const short* Bb = &sh.s.B[cb][0];
        bf16x8 av[4], bv[4];
        #pragma unroll
        for (int n = 0; n < 4; ++n) {
            int col = wc*64 + n*16 + lr;
            int cs = lk ^ ((col >> 1) & 3);
            bv[n] = *(const bf16x8*)&Bb[col*32 + cs*8];
        }
        #pragma unroll
        for (int m = 0; m < 4; ++m) {
            int row = wr*128 + m*16 + lr;
            int cs = lk ^ ((row >> 1) & 3);
            av[m] = *(const bf16x8*)&Ab[row*32 + cs*8];
        }
        if (t < 6) STAGE(nb, t + 2);       // issue-early: latency hides under MFMAs
        __builtin_amdgcn_s_setprio(1);
        #pragma unroll
        for (int m = 0; m < 4; ++m)
            #pragma unroll
            for (int n = 0; n < 4; ++n)
                acc[m][n] = __builtin_amdgcn_mfma_f32_16x16x32_bf16(av[m], bv[n], acc[m][n], 0, 0, 0);
        __builtin_amdgcn_s_setprio(0);
        #pragma unroll
        for (int m = 0; m < 4; ++m) {
            int row = wr*128 + 64 + m*16 + lr;
            int cs = lk ^ ((row >> 1) & 3);
            av[m] = *(const bf16x8*)&Ab[row*32 + cs*8];
        }
        __builtin_amdgcn_s_setprio(1);
        #pragma unroll
        for (int m = 0; m < 4; ++m)
            #pragma unroll
            for (int n = 0; n < 4; ++n)
                acc[4 + m][n] = __builtin_amdgcn_mfma_f32_16x16x32_bf16(av[m], bv[n], acc[4 + m][n], 0, 0, 0);
        __builtin_amdgcn_s_setprio(0);
        // steady state: tile t+1's 4 loads must be done; tile t+2's 4 stay in flight
        if (t < 6) asm volatile("s_waitcnt vmcnt(4)" ::: "memory");
        else       asm volatile("s_waitcnt vmcnt(0)" ::: "memory");
        __builtin_amdgcn_s_barrier();
        __builtin_amdgcn_sched_barrier(0);
        cb = (cb == 2) ? 0 : cb + 1;
        nb = (nb == 2) ? 0 : nb + 1;
    }
#undef STAGE

    __syncthreads();   // full drain before LDS reuse

    // scatter acc -> AHe[(b,j)_local][e*8+h] as bf16 (packed 4-h ds_write_b64)
    #pragma unroll
    for (int m = 0; m < 8; ++m) {
        #pragma unroll
        for (int n = 0; n < 4; ++n) {
            int colC = wc*64 + n*16 + lr;        // (b,e) local
            int bb2 = colC >> 6, e = colC & 63;
            int rowC0 = wr*128 + m*16 + lk*4;    // (j,h) local, 4 consecutive h
            int jj = rowC0 >> 3, h0 = rowC0 & 7;
            ushort4 pk;
            pk.x = f2bf(acc[m][n][0]); pk.y = f2bf(acc[m][n][1]);
            pk.z = f2bf(acc[m][n][2]); pk.w = f2bf(acc[m][n][3]);
            *(ushort4*)&sh.AHe[(bb2*32 + jj)*520 + e*8 + h0] = pk;
        }
    }
    __syncthreads();

    // mini-GEMM: out2[r2][e'] = sum_f AHe[r2][f] * fcwb[e'][f]; M=128, N=64, K=512
    int fm = wid >> 1, fn = wid & 1;
    f32x4 facc[2][2] = {};
    #pragma unroll
    for (int ks = 0; ks < 16; ++ks) {
        int koff = ks*32 + lk*8;
        bf16x8 a0 = *(const bf16x8*)&sh.AHe[(fm*32 + lr)*520 + koff];
        bf16x8 a1 = *(const bf16x8*)&sh.AHe[(fm*32 + 16 + lr)*520 + koff];
        bf16x8 b0 = *(const bf16x8*)&fcwb[(size_t)(fn*32 + lr)*512 + koff];
        bf16x8 b1 = *(const bf16x8*)&fcwb[(size_t)(fn*32 + 16 + lr)*512 + koff];
        facc[0][0] = __builtin_amdgcn_mfma_f32_16x16x32_bf16(a0, b0, facc[0][0], 0, 0, 0);
        facc[0][1] = __builtin_amdgcn_mfma_f32_16x16x32_bf16(a0, b1, facc[0][1], 0, 0, 0);
        facc[1][0] = __builtin_amdgcn_mfma_f32_16x16x32_bf16(a1, b0, facc[1][0], 0, 0, 0);
        facc[1][1] = __builtin_amdgcn_mfma_f32_16x16x32_bf16(a1, b1, facc[1][1], 0, 0, 0);
    }

    int b0g = blockIdx.y * 4;
    float bias0 = fc_b[fn*32 + lr];
    float bias1 = fc_b[fn*32 + 16 + lr];
    #pragma unroll
    for (int am = 0; am < 2; ++am) {
        #pragma unroll
        for (int an = 0; an < 2; ++an) {
            int ecol = fn*32 + an*16 + lr;
            float bias = an ? bias1 : bias0;
            #pragma unroll
            for (int reg = 0; reg < 4; ++reg) {
                int r2 = fm*32 + am*16 + lk*4 + reg;
                int bb2 = r2 >> 5, jj = r2 & 31;
                size_t o = (((size_t)((b0g + bb2)*32 + i_g))*32 + jj)*64 + ecol;
                out[o] = facc[am][an][reg] + bias;
            }
        }
    }
}

extern "C" void kernel_launch(void* const* d_in, const int* in_sizes, int n_in,
                              void* d_out, int out_size, void* d_ws, size_t ws_size,
                              hipStream_t stream) {
    const float* X       = (const float*)d_in[0];
    const float* centers = (const float*)d_in[2];
    const float* spreads = (const float*)d_in[3];
    const float* fc_w    = (const float*)d_in[4];
    const float* fc_b    = (const float*)d_in[5];
    float* out = (float*)d_out;

    char* ws = (char*)d_ws;
    unsigned short* fcwb = (unsigned short*)ws;                 // 64 KB
    unsigned short* X2   = (unsigned short*)(ws + (1 << 20));   // 4 MB
    unsigned short* P2   = (unsigned short*)(ws + (6 << 20));   // 4 MB (8192 x 256)

    k_prep <<<2592, 256, 0, stream>>>(X, fc_w, centers, spreads, X2, fcwb, P2);
    k_gemm <<<dim3(32, 8), 512, 0, stream>>>(P2, X2, fcwb, fc_b, out);
}